// Round 9
// baseline (584.931 us; speedup 1.0000x reference)
//
#include <hip/hip_runtime.h>
#include <math.h>

// ---------------------------------------------------------------------------
// GraphAttentionEmbedding (TGN TransformerConv, H=2, C=64, D=128, EDGE_DIM=256)
//   CSR build: hist -> scan -> fill (perm: slot->edge, srcp: slot->src,
//              relo: rel_t in ORIGINAL edge order)
//   K1 k_node_mfma (ONE launch): staged x-tile [32][128] bf16 in LDS;
//      [Wq|Wk|Wv|Wskip] in registers (wave w owns 64 of 512 cols)
//   K2 k_edge_mfma: staged A-tile [128 edges][256 k] bf16 in LDS (msg loads
//      issued first, cos computed cooperatively while loads fly); We in
//      registers (wave = 32-col group x 4-mtile half); compute = ds_read+MFMA
//   K3 k_agg: wave per dst; 4 edges/iter; no atomics on output
// ---------------------------------------------------------------------------

#define SCALE_ATTN 0.125f
#define SCAN_CHUNK 512

typedef __attribute__((ext_vector_type(8))) short bf16x8;
typedef __attribute__((ext_vector_type(4))) float f32x4;

union AFrag { bf16x8 v; unsigned short u[8]; };

__device__ __forceinline__ unsigned short f2bf(float f) {
    unsigned int u = __float_as_uint(f);
    u += 0x7fffu + ((u >> 16) & 1u);          // RNE
    return (unsigned short)(u >> 16);
}
__device__ __forceinline__ float bf2f(unsigned int lo16) {
    return __uint_as_float(lo16 << 16);
}
__device__ __forceinline__ void unpack8(uint4 u, float* f) {
    f[0] = bf2f(u.x & 0xffffu); f[1] = bf2f(u.x >> 16);
    f[2] = bf2f(u.y & 0xffffu); f[3] = bf2f(u.y >> 16);
    f[4] = bf2f(u.z & 0xffffu); f[5] = bf2f(u.z >> 16);
    f[6] = bf2f(u.w & 0xffffu); f[7] = bf2f(u.w >> 16);
}
__device__ __forceinline__ bf16x8 pack2(float4 a, float4 b) {
    AFrag f;
    f.u[0] = f2bf(a.x); f.u[1] = f2bf(a.y); f.u[2] = f2bf(a.z); f.u[3] = f2bf(a.w);
    f.u[4] = f2bf(b.x); f.u[5] = f2bf(b.y); f.u[6] = f2bf(b.z); f.u[7] = f2bf(b.w);
    return f.v;
}

// ---------------------------------------------------------------------------
// K1: all four node linears in ONE kernel. Block=512 (8 waves), tile=32 nodes.
// LDS: x-tile bf16 [32][128] swizzled (8 KB). Wave w owns 64 cols of the 512
// concatenated outputs (mat = w>>1: q,k,v,skip; half = w&1).
// B in registers: frag[kstep 0..3][nt 0..3] = 64 VGPR; acc[2][4] = 32 VGPR.
// ---------------------------------------------------------------------------
__global__ __launch_bounds__(512, 4) void k_node_mfma(
    const float4* __restrict__ x4,
    const float* __restrict__ Wq, const float* __restrict__ Wk,
    const float* __restrict__ Wv, const float* __restrict__ Ws,
    const float* __restrict__ bq, const float* __restrict__ bk,
    const float* __restrict__ bv, const float* __restrict__ bs,
    unsigned short* __restrict__ qb, unsigned short* __restrict__ kb,
    unsigned short* __restrict__ vb, float* __restrict__ outp,
    int N, int numTiles)
{
    __shared__ __align__(16) unsigned short sX[32 * 128];   // 8 KB
    const int tid = threadIdx.x;
    const int w = tid >> 6, l = tid & 63;
    const int l15 = l & 15, lg = l >> 4;
    const int mat = w >> 1;                 // 0 q, 1 k, 2 v, 3 skip
    const int colbase = (w & 1) * 64;       // within the 128-col matrix

    const float* Wm = (mat == 0) ? Wq : (mat == 1) ? Wk : (mat == 2) ? Wv : Ws;
    const float* bm = (mat == 0) ? bq : (mat == 1) ? bk : (mat == 2) ? bv : bs;

    // B fragments in registers
    bf16x8 Bf[4][4];
    float bias[4];
    #pragma unroll
    for (int nt = 0; nt < 4; ++nt) {
        const int col = colbase + nt * 16 + l15;
        bias[nt] = bm[col];
        #pragma unroll
        for (int ks = 0; ks < 4; ++ks) {
            AFrag f;
            #pragma unroll
            for (int j = 0; j < 8; ++j)
                f.u[j] = f2bf(Wm[(ks * 32 + lg * 8 + j) * 128 + col]);
            Bf[ks][nt] = f.v;
        }
    }

    for (int tile = blockIdx.x; tile < numTiles; tile += gridDim.x) {
        // stage x-tile: 512 threads = 32 nodes x 16 chunks-of-8-floats
        {
            const int e = tid >> 4, k8 = tid & 15;
            const int row = min(tile * 32 + e, N - 1);
            const float4 a0 = x4[(size_t)row * 32 + k8 * 2];
            const float4 a1 = x4[(size_t)row * 32 + k8 * 2 + 1];
            const int byteoff = (e * 256 + k8 * 16) ^ ((e & 7) << 4);
            *(bf16x8*)((char*)sX + byteoff) = pack2(a0, a1);
        }
        __syncthreads();

        f32x4 acc[2][4];
        #pragma unroll
        for (int m = 0; m < 2; ++m)
            #pragma unroll
            for (int nt = 0; nt < 4; ++nt) acc[m][nt] = (f32x4)(0.f);

        #pragma unroll
        for (int m = 0; m < 2; ++m) {
            const int lrow = m * 16 + l15;
            #pragma unroll
            for (int ks = 0; ks < 4; ++ks) {
                const int byteoff = (lrow * 256 + ks * 64 + lg * 16) ^ ((lrow & 7) << 4);
                const bf16x8 a = *(const bf16x8*)((const char*)sX + byteoff);
                #pragma unroll
                for (int nt = 0; nt < 4; ++nt)
                    acc[m][nt] = __builtin_amdgcn_mfma_f32_16x16x32_bf16(a, Bf[ks][nt], acc[m][nt], 0, 0, 0);
            }
        }

        // epilogue
        #pragma unroll
        for (int m = 0; m < 2; ++m) {
            #pragma unroll
            for (int nt = 0; nt < 4; ++nt) {
                const int col = colbase + nt * 16 + l15;
                #pragma unroll
                for (int r = 0; r < 4; ++r) {
                    const int node = tile * 32 + m * 16 + lg * 4 + r;
                    if (node < N) {
                        const float val = acc[m][nt][r] + bias[nt];
                        if (mat == 0)      qb[(size_t)node * 128 + col] = f2bf(val);
                        else if (mat == 1) kb[(size_t)node * 128 + col] = f2bf(val);
                        else if (mat == 2) vb[(size_t)node * 128 + col] = f2bf(val);
                        else               outp[(size_t)node * 128 + col] = val;
                    }
                }
            }
        }
        __syncthreads();
    }
}

// ---------------------------------------------------------------------------
// K2: edge GEMM, staged-A form. Block=512 (8 waves), tile=128 edges.
// LDS: A-tile bf16 [128][256] swizzled (64 KB) -> 2 blocks/CU.
// Stage: msg float4 loads issued FIRST (independent, coalesced), cos-half
// computed cooperatively while loads fly, then msg cvt+write (T14).
// We in registers: wave (g = w&3 col-group of 32, h = w>>2 m-half of 4 tiles);
// Bf[8 kstep][2 nt] = 64 VGPR, acc[4][2] = 32 VGPR.
// Compute: 32 ds_read + 64 MFMA per wave-tile, zero global loads.
// ---------------------------------------------------------------------------
__global__ __launch_bounds__(512, 4) void k_edge_mfma(
    const float4* __restrict__ msg4,
    const float* __restrict__ relo,
    const float4* __restrict__ tw4, const float4* __restrict__ tb4,
    const float* __restrict__ We,
    unsigned short* __restrict__ ebuf, int E, int numTiles)
{
    __shared__ __align__(16) unsigned short sA[128 * 256];   // 64 KB
    const int tid = threadIdx.x;
    const int w = tid >> 6, l = tid & 63;
    const int l15 = l & 15, lg = l >> 4;
    const int g = w & 3;          // col group: cols g*32 .. g*32+31
    const int h = w >> 2;         // m half: m-tiles h*4 .. h*4+3

    // B fragments in registers (K = 256 -> 8 ksteps; 2 n-tiles of 16)
    bf16x8 Bf[8][2];
    #pragma unroll
    for (int ks = 0; ks < 8; ++ks) {
        #pragma unroll
        for (int nt = 0; nt < 2; ++nt) {
            const int col = g * 32 + nt * 16 + l15;
            AFrag f;
            #pragma unroll
            for (int j = 0; j < 8; ++j)
                f.u[j] = f2bf(We[(ks * 32 + lg * 8 + j) * 128 + col]);
            Bf[ks][nt] = f.v;
        }
    }

    for (int tile = blockIdx.x; tile < numTiles; tile += gridDim.x) {
        // ---- stage: issue msg loads first (8 independent coalesced float4)
        float4 mm[8];
        #pragma unroll
        for (int i = 0; i < 4; ++i) {
            const int f8 = tid + i * 512;            // [128 e][16 chunks8]
            const int e = f8 >> 4, k8 = f8 & 15;
            const int sa = min(tile * 128 + e, E - 1);
            mm[i * 2]     = msg4[(size_t)sa * 32 + k8 * 2];
            mm[i * 2 + 1] = msg4[(size_t)sa * 32 + k8 * 2 + 1];
        }
        // ---- cos half while msg loads are in flight
        {
            const int e = tid >> 2, kq = tid & 3;    // 128 e x 4 k-quarters
            const float rel = relo[min(tile * 128 + e, E - 1)];
            #pragma unroll
            for (int jj = 0; jj < 4; ++jj) {
                const float4 tww = tw4[kq * 8 + jj * 2];
                const float4 tw2 = tw4[kq * 8 + jj * 2 + 1];
                const float4 tbb = tb4[kq * 8 + jj * 2];
                const float4 tb2 = tb4[kq * 8 + jj * 2 + 1];
                AFrag c;
                c.u[0] = f2bf(__cosf(fmaf(rel, tww.x, tbb.x)));
                c.u[1] = f2bf(__cosf(fmaf(rel, tww.y, tbb.y)));
                c.u[2] = f2bf(__cosf(fmaf(rel, tww.z, tbb.z)));
                c.u[3] = f2bf(__cosf(fmaf(rel, tww.w, tbb.w)));
                c.u[4] = f2bf(__cosf(fmaf(rel, tw2.x, tb2.x)));
                c.u[5] = f2bf(__cosf(fmaf(rel, tw2.y, tb2.y)));
                c.u[6] = f2bf(__cosf(fmaf(rel, tw2.z, tb2.z)));
                c.u[7] = f2bf(__cosf(fmaf(rel, tw2.w, tb2.w)));
                const int byteoff = (e * 512 + kq * 64 + jj * 16) ^ ((e & 7) << 4);
                *(bf16x8*)((char*)sA + byteoff) = c.v;
            }
        }
        // ---- msg cvt + write (loads have landed under the cos block)
        #pragma unroll
        for (int i = 0; i < 4; ++i) {
            const int f8 = tid + i * 512;
            const int e = f8 >> 4, k8 = f8 & 15;
            const int byteoff = (e * 512 + 256 + k8 * 16) ^ ((e & 7) << 4);
            *(bf16x8*)((char*)sA + byteoff) = pack2(mm[i * 2], mm[i * 2 + 1]);
        }
        __syncthreads();

        // ---- compute: pure ds_read + MFMA
        f32x4 acc[4][2];
        #pragma unroll
        for (int m = 0; m < 4; ++m)
            #pragma unroll
            for (int nt = 0; nt < 2; ++nt) acc[m][nt] = (f32x4)(0.f);

        #pragma unroll
        for (int m = 0; m < 4; ++m) {
            const int row = (h * 4 + m) * 16 + l15;
            #pragma unroll
            for (int ks = 0; ks < 8; ++ks) {
                const int byteoff = (row * 512 + ks * 64 + lg * 16) ^ ((row & 7) << 4);
                const bf16x8 a = *(const bf16x8*)((const char*)sA + byteoff);
                acc[m][0] = __builtin_amdgcn_mfma_f32_16x16x32_bf16(a, Bf[ks][0], acc[m][0], 0, 0, 0);
                acc[m][1] = __builtin_amdgcn_mfma_f32_16x16x32_bf16(a, Bf[ks][1], acc[m][1], 0, 0, 0);
            }
        }

        // ---- epilogue: sequential rows (coverage by construction)
        #pragma unroll
        for (int m = 0; m < 4; ++m) {
            #pragma unroll
            for (int nt = 0; nt < 2; ++nt) {
                const int col = g * 32 + nt * 16 + l15;
                #pragma unroll
                for (int r = 0; r < 4; ++r) {
                    const int er = tile * 128 + (h * 4 + m) * 16 + lg * 4 + r;
                    if (er < E) ebuf[(size_t)er * 128 + col] = f2bf(acc[m][nt][r]);
                }
            }
        }
        __syncthreads();
    }
}

// ---------------------------------------------------------------------------
// CSR build
// ---------------------------------------------------------------------------
__global__ __launch_bounds__(256) void k_hist(
    const int* __restrict__ ei, int* __restrict__ counts, int E)
{
    int i = blockIdx.x * 256 + threadIdx.x;
    if (i < E) atomicAdd(&counts[ei[E + i]], 1);
}

__global__ __launch_bounds__(256) void k_scan_partial(
    const int* __restrict__ counts, int* __restrict__ partial, int N)
{
    const int base = blockIdx.x * SCAN_CHUNK;
    int v = 0;
    for (int i = threadIdx.x; i < SCAN_CHUNK; i += 256) {
        const int idx = base + i;
        if (idx < N) v += counts[idx];
    }
    __shared__ int red[4];
    #pragma unroll
    for (int off = 1; off < 64; off <<= 1) v += __shfl_xor(v, off);
    if ((threadIdx.x & 63) == 0) red[threadIdx.x >> 6] = v;
    __syncthreads();
    if (threadIdx.x == 0) partial[blockIdx.x] = red[0] + red[1] + red[2] + red[3];
}

__global__ __launch_bounds__(256) void k_scan_base(
    const int* __restrict__ partial, int* __restrict__ base, int nb)
{
    __shared__ int tmp[256];
    const int v = (threadIdx.x < nb) ? partial[threadIdx.x] : 0;
    tmp[threadIdx.x] = v;
    __syncthreads();
    for (int off = 1; off < 256; off <<= 1) {
        const int add = (threadIdx.x >= off) ? tmp[threadIdx.x - off] : 0;
        __syncthreads();
        tmp[threadIdx.x] += add;
        __syncthreads();
    }
    if (threadIdx.x < nb) base[threadIdx.x] = tmp[threadIdx.x] - v;
}

__global__ __launch_bounds__(256) void k_scan_final(
    const int* __restrict__ counts, const int* __restrict__ base,
    int* __restrict__ rowptr, int* __restrict__ cursor, int N)
{
    const int i0 = blockIdx.x * SCAN_CHUNK;
    __shared__ int tmp[256];
    const int ia = i0 + threadIdx.x * 2, ib = ia + 1;
    const int v0 = (ia < N) ? counts[ia] : 0;
    const int v1 = (ib < N) ? counts[ib] : 0;
    const int s = v0 + v1;
    tmp[threadIdx.x] = s;
    __syncthreads();
    for (int off = 1; off < 256; off <<= 1) {
        const int add = (threadIdx.x >= off) ? tmp[threadIdx.x - off] : 0;
        __syncthreads();
        tmp[threadIdx.x] += add;
        __syncthreads();
    }
    const int excl = tmp[threadIdx.x] - s + base[blockIdx.x];
    if (ia < N) { rowptr[ia] = excl;      cursor[ia] = excl; }
    if (ib < N) { rowptr[ib] = excl + v0; cursor[ib] = excl + v0; }
}

// fill: perm (slot -> edge), srcp (slot -> src), relo (original edge order)
__global__ __launch_bounds__(256) void k_fill(
    const int* __restrict__ ei, const float* __restrict__ t,
    const float* __restrict__ lu, int* __restrict__ cursor,
    int* __restrict__ perm, int* __restrict__ srcp,
    float* __restrict__ relo, int E)
{
    int i = blockIdx.x * 256 + threadIdx.x;
    if (i < E) {
        const int s = ei[i];
        const int d = ei[E + i];
        const int pos = atomicAdd(&cursor[d], 1);
        perm[pos] = i;
        srcp[pos] = s;
        relo[i] = t[i] - lu[s];
    }
}

// ---------------------------------------------------------------------------
// K3: fused aggregation. One wave per dst. Lane = (eg = l>>4 edge group,
// s16 = l&15 16B slot in the 256B row). 4 edges per iteration, 3 independent
// uint4 loads each. Logit reduce xor{1,2,4} within the 8-lane head slice;
// final cross-group combine xor{16,32}.
// ---------------------------------------------------------------------------
__global__ __launch_bounds__(256) void k_agg(
    const int* __restrict__ srcp, const int* __restrict__ perm,
    const int* __restrict__ rowptr, const int* __restrict__ counts,
    const uint4* __restrict__ qb4, const uint4* __restrict__ kb4,
    const uint4* __restrict__ vb4, const uint4* __restrict__ eb4,
    float4* __restrict__ out4, int N)
{
    const int d = blockIdx.x * 4 + (threadIdx.x >> 6);
    if (d >= N) return;
    const int l = threadIdx.x & 63;
    const int s16 = l & 15;       // 16B slot (8 channels)
    const int eg = l >> 4;        // edge group 0..3
    const int start = rowptr[d];
    const int deg = counts[d];

    float qf[8];
    unpack8(qb4[(size_t)d * 16 + s16], qf);
    float accf[8] = {0.f, 0.f, 0.f, 0.f, 0.f, 0.f, 0.f, 0.f};
    float denom = 0.f;

    for (int cbase = 0; cbase < deg; cbase += 64) {
        const int clen = min(deg - cbase, 64);
        int mySrc = 0, myEid = 0;
        if (l < clen) {
            mySrc = srcp[start + cbase + l];   // coalesced
            myEid = perm[start + cbase + l];   // coalesced
        }

        #pragma unroll 2
        for (int i = 0; i < clen; i += 4) {
            const int off = i + eg;
            const bool valid = off < clen;
            const int offc = valid ? off : 0;
            const int src = __shfl(mySrc, offc);
            const int eid = __shfl(myEid, offc);
            float kf[8], ef[8], vf[8];
            unpack8(kb4[(size_t)src * 16 + s16], kf);
            unpack8(eb4[(size_t)eid * 16 + s16], ef);
            unpack8(vb4[(size_t)src * 16 + s16], vf);
            float s = 0.f;
            #pragma unroll
            for (int j = 0; j < 8; ++j) s = fmaf(qf[j], kf[j] + ef[j], s);
            s += __shfl_xor(s, 1);
            s += __shfl_xor(s, 2);
            s += __shfl_xor(s, 4);
            const float p = valid ? __expf(s * SCALE_ATTN) : 0.f;
            denom += p;
            #pragma unroll
            for (int j = 0; j < 8; ++j) accf[j] = fmaf(p, vf[j] + ef[j], accf[j]);
        }
    }
    #pragma unroll
    for (int j = 0; j < 8; ++j) {
        accf[j] += __shfl_xor(accf[j], 16);
        accf[j] += __shfl_xor(accf[j], 32);
    }
    denom += __shfl_xor(denom, 16);
    denom += __shfl_xor(denom, 32);

    if (l < 16) {
        const float inv = 1.f / (denom + 1e-16f);
        float4* o = out4 + (size_t)d * 32 + s16 * 2;
        const float4 c0 = o[0];
        const float4 c1 = o[1];
        o[0] = make_float4(fmaf(accf[0], inv, c0.x), fmaf(accf[1], inv, c0.y),
                           fmaf(accf[2], inv, c0.z), fmaf(accf[3], inv, c0.w));
        o[1] = make_float4(fmaf(accf[4], inv, c1.x), fmaf(accf[5], inv, c1.y),
                           fmaf(accf[6], inv, c1.z), fmaf(accf[7], inv, c1.w));
    }
}

// ---------------------------------------------------------------------------
extern "C" void kernel_launch(void* const* d_in, const int* in_sizes, int n_in,
                              void* d_out, int out_size, void* d_ws, size_t ws_size,
                              hipStream_t stream)
{
    const float* x   = (const float*)d_in[0];
    const float* lu  = (const float*)d_in[1];
    const int*   ei  = (const int*)d_in[2];
    const float* t   = (const float*)d_in[3];
    const float* msg = (const float*)d_in[4];
    const float* tw  = (const float*)d_in[5];
    const float* tb  = (const float*)d_in[6];
    const float* Wq  = (const float*)d_in[7];
    const float* bq  = (const float*)d_in[8];
    const float* Wk  = (const float*)d_in[9];
    const float* bk  = (const float*)d_in[10];
    const float* Wv  = (const float*)d_in[11];
    const float* bv  = (const float*)d_in[12];
    const float* We  = (const float*)d_in[13];
    const float* Wsk = (const float*)d_in[14];
    const float* bsk = (const float*)d_in[15];

    const int N = in_sizes[1];   // last_update: N elements
    const int E = in_sizes[3];   // t: E elements
    float* out = (float*)d_out;

    char* ws = (char*)d_ws;
    unsigned short* qb = (unsigned short*)ws;  ws += (size_t)N * 128 * sizeof(unsigned short);
    unsigned short* kb = (unsigned short*)ws;  ws += (size_t)N * 128 * sizeof(unsigned short);
    unsigned short* vb = (unsigned short*)ws;  ws += (size_t)N * 128 * sizeof(unsigned short);
    unsigned short* eb = (unsigned short*)ws;  ws += (size_t)E * 128 * sizeof(unsigned short);
    int*   counts  = (int*)ws;   ws += (size_t)N * sizeof(int);
    int*   rowptr  = (int*)ws;   ws += (size_t)N * sizeof(int);
    int*   cursor  = (int*)ws;   ws += (size_t)N * sizeof(int);
    int*   perm    = (int*)ws;   ws += (size_t)E * sizeof(int);
    int*   srcp    = (int*)ws;   ws += (size_t)E * sizeof(int);
    float* relo    = (float*)ws; ws += (size_t)E * sizeof(float);
    int*   partial = (int*)ws;   ws += 512 * sizeof(int);
    int*   baseArr = (int*)ws;   ws += 512 * sizeof(int);

    const int nScan = (N + SCAN_CHUNK - 1) / SCAN_CHUNK;

    hipMemsetAsync(counts, 0, (size_t)N * sizeof(int), stream);

    // CSR build (k_edge needs relo; k_agg needs perm/srcp/rowptr/counts)
    k_hist<<<(E + 255) / 256, 256, 0, stream>>>(ei, counts, E);
    k_scan_partial<<<nScan, 256, 0, stream>>>(counts, partial, N);
    k_scan_base<<<1, 256, 0, stream>>>(partial, baseArr, nScan);
    k_scan_final<<<nScan, 256, 0, stream>>>(counts, baseArr, rowptr, cursor, N);
    k_fill<<<(E + 255) / 256, 256, 0, stream>>>(ei, t, lu, cursor, perm, srcp, relo, E);

    // node linears: q/k/v/skip in ONE staged-x launch
    const int nTN = (N + 31) / 32;
    k_node_mfma<<<min(nTN, 1024), 512, 0, stream>>>(
        (const float4*)x, Wq, Wk, Wv, Wsk, bq, bk, bv, bsk,
        qb, kb, vb, out, N, nTN);

    // edge GEMM: staged-A, original edge order (sequential reads + writes)
    const int nTE = (E + 127) / 128;
    k_edge_mfma<<<min(nTE, 1024), 512, 0, stream>>>(
        (const float4*)msg, relo,
        (const float4*)tw, (const float4*)tb, We, eb, E, nTE);

    // fused aggregation (e gathered via perm; no atomics)
    k_agg<<<(N + 3) / 4, 256, 0, stream>>>(
        srcp, perm, rowptr, counts,
        (const uint4*)qb, (const uint4*)kb, (const uint4*)vb, (const uint4*)eb,
        (float4*)out, N);
}

// Round 10
// 428.116 us; speedup vs baseline: 1.3663x; 1.3663x over previous
//
#include <hip/hip_runtime.h>
#include <math.h>

// ---------------------------------------------------------------------------
// GraphAttentionEmbedding (TGN TransformerConv, H=2, C=64, D=128, EDGE_DIM=256)
//   CSR build: hist -> scan -> fill (perm: slot->edge, srcp: slot->src,
//              relo: rel_t in ORIGINAL edge order)
//   K1 k_node_mfma (ONE launch): staged x-tile [32][128] bf16 in LDS;
//      [Wq|Wk|Wv|Wskip] in registers (wave w owns 64 of 512 cols)  [R9 proven]
//   K2 k_edge_mfma: R7 per-lane-gather structure, widened to 32 edges/wave
//      (2 independent m-subtiles): 4 independent msg loads per kk covered by
//      2 cos blocks + 32 MFMAs; no long-lived prefetch state (no spill)
//   K3 k_agg: wave per dst; 4 edges/iter; no atomics on output  [R9 proven]
// ---------------------------------------------------------------------------

#define SCALE_ATTN 0.125f
#define SCAN_CHUNK 512

typedef __attribute__((ext_vector_type(8))) short bf16x8;
typedef __attribute__((ext_vector_type(4))) float f32x4;

union AFrag { bf16x8 v; unsigned short u[8]; };

__device__ __forceinline__ unsigned short f2bf(float f) {
    unsigned int u = __float_as_uint(f);
    u += 0x7fffu + ((u >> 16) & 1u);          // RNE
    return (unsigned short)(u >> 16);
}
__device__ __forceinline__ float bf2f(unsigned int lo16) {
    return __uint_as_float(lo16 << 16);
}
__device__ __forceinline__ void unpack8(uint4 u, float* f) {
    f[0] = bf2f(u.x & 0xffffu); f[1] = bf2f(u.x >> 16);
    f[2] = bf2f(u.y & 0xffffu); f[3] = bf2f(u.y >> 16);
    f[4] = bf2f(u.z & 0xffffu); f[5] = bf2f(u.z >> 16);
    f[6] = bf2f(u.w & 0xffffu); f[7] = bf2f(u.w >> 16);
}
__device__ __forceinline__ bf16x8 pack2(float4 a, float4 b) {
    AFrag f;
    f.u[0] = f2bf(a.x); f.u[1] = f2bf(a.y); f.u[2] = f2bf(a.z); f.u[3] = f2bf(a.w);
    f.u[4] = f2bf(b.x); f.u[5] = f2bf(b.y); f.u[6] = f2bf(b.z); f.u[7] = f2bf(b.w);
    return f.v;
}

// ---------------------------------------------------------------------------
// K1: all four node linears in ONE kernel. Block=512 (8 waves), tile=32 nodes.
// LDS: x-tile bf16 [32][128] swizzled (8 KB). Wave w owns 64 cols of the 512
// concatenated outputs (mat = w>>1: q,k,v,skip; half = w&1).
// ---------------------------------------------------------------------------
__global__ __launch_bounds__(512, 4) void k_node_mfma(
    const float4* __restrict__ x4,
    const float* __restrict__ Wq, const float* __restrict__ Wk,
    const float* __restrict__ Wv, const float* __restrict__ Ws,
    const float* __restrict__ bq, const float* __restrict__ bk,
    const float* __restrict__ bv, const float* __restrict__ bs,
    unsigned short* __restrict__ qb, unsigned short* __restrict__ kb,
    unsigned short* __restrict__ vb, float* __restrict__ outp,
    int N, int numTiles)
{
    __shared__ __align__(16) unsigned short sX[32 * 128];   // 8 KB
    const int tid = threadIdx.x;
    const int w = tid >> 6, l = tid & 63;
    const int l15 = l & 15, lg = l >> 4;
    const int mat = w >> 1;                 // 0 q, 1 k, 2 v, 3 skip
    const int colbase = (w & 1) * 64;       // within the 128-col matrix

    const float* Wm = (mat == 0) ? Wq : (mat == 1) ? Wk : (mat == 2) ? Wv : Ws;
    const float* bm = (mat == 0) ? bq : (mat == 1) ? bk : (mat == 2) ? bv : bs;

    // B fragments in registers
    bf16x8 Bf[4][4];
    float bias[4];
    #pragma unroll
    for (int nt = 0; nt < 4; ++nt) {
        const int col = colbase + nt * 16 + l15;
        bias[nt] = bm[col];
        #pragma unroll
        for (int ks = 0; ks < 4; ++ks) {
            AFrag f;
            #pragma unroll
            for (int j = 0; j < 8; ++j)
                f.u[j] = f2bf(Wm[(ks * 32 + lg * 8 + j) * 128 + col]);
            Bf[ks][nt] = f.v;
        }
    }

    for (int tile = blockIdx.x; tile < numTiles; tile += gridDim.x) {
        {
            const int e = tid >> 4, k8 = tid & 15;
            const int row = min(tile * 32 + e, N - 1);
            const float4 a0 = x4[(size_t)row * 32 + k8 * 2];
            const float4 a1 = x4[(size_t)row * 32 + k8 * 2 + 1];
            const int byteoff = (e * 256 + k8 * 16) ^ ((e & 7) << 4);
            *(bf16x8*)((char*)sX + byteoff) = pack2(a0, a1);
        }
        __syncthreads();

        f32x4 acc[2][4];
        #pragma unroll
        for (int m = 0; m < 2; ++m)
            #pragma unroll
            for (int nt = 0; nt < 4; ++nt) acc[m][nt] = (f32x4)(0.f);

        #pragma unroll
        for (int m = 0; m < 2; ++m) {
            const int lrow = m * 16 + l15;
            #pragma unroll
            for (int ks = 0; ks < 4; ++ks) {
                const int byteoff = (lrow * 256 + ks * 64 + lg * 16) ^ ((lrow & 7) << 4);
                const bf16x8 a = *(const bf16x8*)((const char*)sX + byteoff);
                #pragma unroll
                for (int nt = 0; nt < 4; ++nt)
                    acc[m][nt] = __builtin_amdgcn_mfma_f32_16x16x32_bf16(a, Bf[ks][nt], acc[m][nt], 0, 0, 0);
            }
        }

        #pragma unroll
        for (int m = 0; m < 2; ++m) {
            #pragma unroll
            for (int nt = 0; nt < 4; ++nt) {
                const int col = colbase + nt * 16 + l15;
                #pragma unroll
                for (int r = 0; r < 4; ++r) {
                    const int node = tile * 32 + m * 16 + lg * 4 + r;
                    if (node < N) {
                        const float val = acc[m][nt][r] + bias[nt];
                        if (mat == 0)      qb[(size_t)node * 128 + col] = f2bf(val);
                        else if (mat == 1) kb[(size_t)node * 128 + col] = f2bf(val);
                        else if (mat == 2) vb[(size_t)node * 128 + col] = f2bf(val);
                        else               outp[(size_t)node * 128 + col] = val;
                    }
                }
            }
        }
        __syncthreads();
    }
}

// ---------------------------------------------------------------------------
// K2: edge GEMM via MFMA in ORIGINAL edge order, R7 structure widened.
// LDS: We^T bf16 [n=128][k=256] swizzled (64 KB). 512 thr = 8 waves,
// tile = 256 edges, 32 edges/wave as 2 independent m-subtiles.
// Per kk: 4 independent msg float4 loads, covered by 2 cos blocks + 32 MFMA.
// No prefetch state held across kk iterations -> no spill.
// ---------------------------------------------------------------------------
__global__ __launch_bounds__(512, 4) void k_edge_mfma(
    const float4* __restrict__ msg4,
    const float* __restrict__ relo,
    const float4* __restrict__ tw4, const float4* __restrict__ tb4,
    const float* __restrict__ We,
    unsigned short* __restrict__ ebuf, int E, int numTiles)
{
    __shared__ __align__(16) unsigned short sWe[128 * 256];   // 64 KB
    const int tid = threadIdx.x;
    const int w = tid >> 6, l = tid & 63;
    const int l15 = l & 15, lg = l >> 4;

    for (int c = tid; c < 4096; c += 512) {
        const int n = c >> 5, k0 = (c & 31) << 3;
        AFrag af;
        #pragma unroll
        for (int j = 0; j < 8; ++j) af.u[j] = f2bf(We[(k0 + j) * 128 + n]);
        const int byteoff = ((n << 9) + (k0 << 1)) ^ ((n & 7) << 4);
        *(bf16x8*)((char*)sWe + byteoff) = af.v;
    }
    __syncthreads();

    for (int tile = blockIdx.x; tile < numTiles; tile += gridDim.x) {
        const int ebase = tile * 256 + w * 32;
        const int sa0 = min(ebase + l15, E - 1);
        const int sa1 = min(ebase + 16 + l15, E - 1);
        const float rel0 = relo[sa0];
        const float rel1 = relo[sa1];

        f32x4 acc0[8], acc1[8];
        #pragma unroll
        for (int i = 0; i < 8; ++i) { acc0[i] = (f32x4)(0.f); acc1[i] = (f32x4)(0.f); }

        #pragma unroll 1
        for (int kk = 0; kk < 4; ++kk) {
            const int kbase = (kk << 5) + (lg << 3);

            // 4 independent msg loads for the two edge subtiles
            const float4 m00 = msg4[(size_t)sa0 * 32 + (kbase >> 2)];
            const float4 m01 = msg4[(size_t)sa0 * 32 + (kbase >> 2) + 1];
            const float4 m10 = msg4[(size_t)sa1 * 32 + (kbase >> 2)];
            const float4 m11 = msg4[(size_t)sa1 * 32 + (kbase >> 2) + 1];

            const float4 tww = tw4[kbase >> 2];
            const float4 tw2 = tw4[(kbase >> 2) + 1];
            const float4 tbb = tb4[kbase >> 2];
            const float4 tb2 = tb4[(kbase >> 2) + 1];
            const int bbaseC = ((l15 << 9) + (kbase << 1)) ^ ((l & 7) << 4);
            const int bbaseM = ((l15 << 9) + ((128 + kbase) << 1)) ^ ((l & 7) << 4);

            // cos block, edge subtile 0 (covers msg latency)
            AFrag a0;
            a0.u[0] = f2bf(__cosf(fmaf(rel0, tww.x, tbb.x)));
            a0.u[1] = f2bf(__cosf(fmaf(rel0, tww.y, tbb.y)));
            a0.u[2] = f2bf(__cosf(fmaf(rel0, tww.z, tbb.z)));
            a0.u[3] = f2bf(__cosf(fmaf(rel0, tww.w, tbb.w)));
            a0.u[4] = f2bf(__cosf(fmaf(rel0, tw2.x, tb2.x)));
            a0.u[5] = f2bf(__cosf(fmaf(rel0, tw2.y, tb2.y)));
            a0.u[6] = f2bf(__cosf(fmaf(rel0, tw2.z, tb2.z)));
            a0.u[7] = f2bf(__cosf(fmaf(rel0, tw2.w, tb2.w)));
            #pragma unroll
            for (int nt = 0; nt < 8; ++nt) {
                const bf16x8 b = *(const bf16x8*)((const char*)sWe + (bbaseC + (nt << 13)));
                acc0[nt] = __builtin_amdgcn_mfma_f32_16x16x32_bf16(a0.v, b, acc0[nt], 0, 0, 0);
            }

            // cos block, edge subtile 1
            AFrag a1;
            a1.u[0] = f2bf(__cosf(fmaf(rel1, tww.x, tbb.x)));
            a1.u[1] = f2bf(__cosf(fmaf(rel1, tww.y, tbb.y)));
            a1.u[2] = f2bf(__cosf(fmaf(rel1, tww.z, tbb.z)));
            a1.u[3] = f2bf(__cosf(fmaf(rel1, tww.w, tbb.w)));
            a1.u[4] = f2bf(__cosf(fmaf(rel1, tw2.x, tb2.x)));
            a1.u[5] = f2bf(__cosf(fmaf(rel1, tw2.y, tb2.y)));
            a1.u[6] = f2bf(__cosf(fmaf(rel1, tw2.z, tb2.z)));
            a1.u[7] = f2bf(__cosf(fmaf(rel1, tw2.w, tb2.w)));
            #pragma unroll
            for (int nt = 0; nt < 8; ++nt) {
                const bf16x8 b = *(const bf16x8*)((const char*)sWe + (bbaseC + (nt << 13)));
                acc1[nt] = __builtin_amdgcn_mfma_f32_16x16x32_bf16(a1.v, b, acc1[nt], 0, 0, 0);
            }

            // msg halves (loads landed under the cos blocks)
            const bf16x8 am0 = pack2(m00, m01);
            #pragma unroll
            for (int nt = 0; nt < 8; ++nt) {
                const bf16x8 b = *(const bf16x8*)((const char*)sWe + (bbaseM + (nt << 13)));
                acc0[nt] = __builtin_amdgcn_mfma_f32_16x16x32_bf16(am0, b, acc0[nt], 0, 0, 0);
            }
            const bf16x8 am1 = pack2(m10, m11);
            #pragma unroll
            for (int nt = 0; nt < 8; ++nt) {
                const bf16x8 b = *(const bf16x8*)((const char*)sWe + (bbaseM + (nt << 13)));
                acc1[nt] = __builtin_amdgcn_mfma_f32_16x16x32_bf16(am1, b, acc1[nt], 0, 0, 0);
            }
        }

        // epilogue: sequential rows (coverage by construction)
        #pragma unroll
        for (int nt = 0; nt < 8; ++nt) {
            const int col = (nt << 4) + l15;
            #pragma unroll
            for (int r = 0; r < 4; ++r) {
                const int er0 = ebase + (lg << 2) + r;
                const int er1 = er0 + 16;
                if (er0 < E) ebuf[(size_t)er0 * 128 + col] = f2bf(acc0[nt][r]);
                if (er1 < E) ebuf[(size_t)er1 * 128 + col] = f2bf(acc1[nt][r]);
            }
        }
    }
}

// ---------------------------------------------------------------------------
// CSR build
// ---------------------------------------------------------------------------
__global__ __launch_bounds__(256) void k_hist(
    const int* __restrict__ ei, int* __restrict__ counts, int E)
{
    int i = blockIdx.x * 256 + threadIdx.x;
    if (i < E) atomicAdd(&counts[ei[E + i]], 1);
}

__global__ __launch_bounds__(256) void k_scan_partial(
    const int* __restrict__ counts, int* __restrict__ partial, int N)
{
    const int base = blockIdx.x * SCAN_CHUNK;
    int v = 0;
    for (int i = threadIdx.x; i < SCAN_CHUNK; i += 256) {
        const int idx = base + i;
        if (idx < N) v += counts[idx];
    }
    __shared__ int red[4];
    #pragma unroll
    for (int off = 1; off < 64; off <<= 1) v += __shfl_xor(v, off);
    if ((threadIdx.x & 63) == 0) red[threadIdx.x >> 6] = v;
    __syncthreads();
    if (threadIdx.x == 0) partial[blockIdx.x] = red[0] + red[1] + red[2] + red[3];
}

__global__ __launch_bounds__(256) void k_scan_base(
    const int* __restrict__ partial, int* __restrict__ base, int nb)
{
    __shared__ int tmp[256];
    const int v = (threadIdx.x < nb) ? partial[threadIdx.x] : 0;
    tmp[threadIdx.x] = v;
    __syncthreads();
    for (int off = 1; off < 256; off <<= 1) {
        const int add = (threadIdx.x >= off) ? tmp[threadIdx.x - off] : 0;
        __syncthreads();
        tmp[threadIdx.x] += add;
        __syncthreads();
    }
    if (threadIdx.x < nb) base[threadIdx.x] = tmp[threadIdx.x] - v;
}

__global__ __launch_bounds__(256) void k_scan_final(
    const int* __restrict__ counts, const int* __restrict__ base,
    int* __restrict__ rowptr, int* __restrict__ cursor, int N)
{
    const int i0 = blockIdx.x * SCAN_CHUNK;
    __shared__ int tmp[256];
    const int ia = i0 + threadIdx.x * 2, ib = ia + 1;
    const int v0 = (ia < N) ? counts[ia] : 0;
    const int v1 = (ib < N) ? counts[ib] : 0;
    const int s = v0 + v1;
    tmp[threadIdx.x] = s;
    __syncthreads();
    for (int off = 1; off < 256; off <<= 1) {
        const int add = (threadIdx.x >= off) ? tmp[threadIdx.x - off] : 0;
        __syncthreads();
        tmp[threadIdx.x] += add;
        __syncthreads();
    }
    const int excl = tmp[threadIdx.x] - s + base[blockIdx.x];
    if (ia < N) { rowptr[ia] = excl;      cursor[ia] = excl; }
    if (ib < N) { rowptr[ib] = excl + v0; cursor[ib] = excl + v0; }
}

// fill: perm (slot -> edge), srcp (slot -> src), relo (original edge order)
__global__ __launch_bounds__(256) void k_fill(
    const int* __restrict__ ei, const float* __restrict__ t,
    const float* __restrict__ lu, int* __restrict__ cursor,
    int* __restrict__ perm, int* __restrict__ srcp,
    float* __restrict__ relo, int E)
{
    int i = blockIdx.x * 256 + threadIdx.x;
    if (i < E) {
        const int s = ei[i];
        const int d = ei[E + i];
        const int pos = atomicAdd(&cursor[d], 1);
        perm[pos] = i;
        srcp[pos] = s;
        relo[i] = t[i] - lu[s];
    }
}

// ---------------------------------------------------------------------------
// K3: fused aggregation. One wave per dst. Lane = (eg = l>>4 edge group,
// s16 = l&15 16B slot in the 256B row). 4 edges per iteration, 3 independent
// uint4 loads each. Logit reduce xor{1,2,4} within the 8-lane head slice;
// final cross-group combine xor{16,32}.
// ---------------------------------------------------------------------------
__global__ __launch_bounds__(256) void k_agg(
    const int* __restrict__ srcp, const int* __restrict__ perm,
    const int* __restrict__ rowptr, const int* __restrict__ counts,
    const uint4* __restrict__ qb4, const uint4* __restrict__ kb4,
    const uint4* __restrict__ vb4, const uint4* __restrict__ eb4,
    float4* __restrict__ out4, int N)
{
    const int d = blockIdx.x * 4 + (threadIdx.x >> 6);
    if (d >= N) return;
    const int l = threadIdx.x & 63;
    const int s16 = l & 15;       // 16B slot (8 channels)
    const int eg = l >> 4;        // edge group 0..3
    const int start = rowptr[d];
    const int deg = counts[d];

    float qf[8];
    unpack8(qb4[(size_t)d * 16 + s16], qf);
    float accf[8] = {0.f, 0.f, 0.f, 0.f, 0.f, 0.f, 0.f, 0.f};
    float denom = 0.f;

    for (int cbase = 0; cbase < deg; cbase += 64) {
        const int clen = min(deg - cbase, 64);
        int mySrc = 0, myEid = 0;
        if (l < clen) {
            mySrc = srcp[start + cbase + l];   // coalesced
            myEid = perm[start + cbase + l];   // coalesced
        }

        #pragma unroll 2
        for (int i = 0; i < clen; i += 4) {
            const int off = i + eg;
            const bool valid = off < clen;
            const int offc = valid ? off : 0;
            const int src = __shfl(mySrc, offc);
            const int eid = __shfl(myEid, offc);
            float kf[8], ef[8], vf[8];
            unpack8(kb4[(size_t)src * 16 + s16], kf);
            unpack8(eb4[(size_t)eid * 16 + s16], ef);
            unpack8(vb4[(size_t)src * 16 + s16], vf);
            float s = 0.f;
            #pragma unroll
            for (int j = 0; j < 8; ++j) s = fmaf(qf[j], kf[j] + ef[j], s);
            s += __shfl_xor(s, 1);
            s += __shfl_xor(s, 2);
            s += __shfl_xor(s, 4);
            const float p = valid ? __expf(s * SCALE_ATTN) : 0.f;
            denom += p;
            #pragma unroll
            for (int j = 0; j < 8; ++j) accf[j] = fmaf(p, vf[j] + ef[j], accf[j]);
        }
    }
    #pragma unroll
    for (int j = 0; j < 8; ++j) {
        accf[j] += __shfl_xor(accf[j], 16);
        accf[j] += __shfl_xor(accf[j], 32);
    }
    denom += __shfl_xor(denom, 16);
    denom += __shfl_xor(denom, 32);

    if (l < 16) {
        const float inv = 1.f / (denom + 1e-16f);
        float4* o = out4 + (size_t)d * 32 + s16 * 2;
        const float4 c0 = o[0];
        const float4 c1 = o[1];
        o[0] = make_float4(fmaf(accf[0], inv, c0.x), fmaf(accf[1], inv, c0.y),
                           fmaf(accf[2], inv, c0.z), fmaf(accf[3], inv, c0.w));
        o[1] = make_float4(fmaf(accf[4], inv, c1.x), fmaf(accf[5], inv, c1.y),
                           fmaf(accf[6], inv, c1.z), fmaf(accf[7], inv, c1.w));
    }
}

// ---------------------------------------------------------------------------
extern "C" void kernel_launch(void* const* d_in, const int* in_sizes, int n_in,
                              void* d_out, int out_size, void* d_ws, size_t ws_size,
                              hipStream_t stream)
{
    const float* x   = (const float*)d_in[0];
    const float* lu  = (const float*)d_in[1];
    const int*   ei  = (const int*)d_in[2];
    const float* t   = (const float*)d_in[3];
    const float* msg = (const float*)d_in[4];
    const float* tw  = (const float*)d_in[5];
    const float* tb  = (const float*)d_in[6];
    const float* Wq  = (const float*)d_in[7];
    const float* bq  = (const float*)d_in[8];
    const float* Wk  = (const float*)d_in[9];
    const float* bk  = (const float*)d_in[10];
    const float* Wv  = (const float*)d_in[11];
    const float* bv  = (const float*)d_in[12];
    const float* We  = (const float*)d_in[13];
    const float* Wsk = (const float*)d_in[14];
    const float* bsk = (const float*)d_in[15];

    const int N = in_sizes[1];   // last_update: N elements
    const int E = in_sizes[3];   // t: E elements
    float* out = (float*)d_out;

    char* ws = (char*)d_ws;
    unsigned short* qb = (unsigned short*)ws;  ws += (size_t)N * 128 * sizeof(unsigned short);
    unsigned short* kb = (unsigned short*)ws;  ws += (size_t)N * 128 * sizeof(unsigned short);
    unsigned short* vb = (unsigned short*)ws;  ws += (size_t)N * 128 * sizeof(unsigned short);
    unsigned short* eb = (unsigned short*)ws;  ws += (size_t)E * 128 * sizeof(unsigned short);
    int*   counts  = (int*)ws;   ws += (size_t)N * sizeof(int);
    int*   rowptr  = (int*)ws;   ws += (size_t)N * sizeof(int);
    int*   cursor  = (int*)ws;   ws += (size_t)N * sizeof(int);
    int*   perm    = (int*)ws;   ws += (size_t)E * sizeof(int);
    int*   srcp    = (int*)ws;   ws += (size_t)E * sizeof(int);
    float* relo    = (float*)ws; ws += (size_t)E * sizeof(float);
    int*   partial = (int*)ws;   ws += 512 * sizeof(int);
    int*   baseArr = (int*)ws;   ws += 512 * sizeof(int);

    const int nScan = (N + SCAN_CHUNK - 1) / SCAN_CHUNK;

    hipMemsetAsync(counts, 0, (size_t)N * sizeof(int), stream);

    // CSR build (k_edge needs relo; k_agg needs perm/srcp/rowptr/counts)
    k_hist<<<(E + 255) / 256, 256, 0, stream>>>(ei, counts, E);
    k_scan_partial<<<nScan, 256, 0, stream>>>(counts, partial, N);
    k_scan_base<<<1, 256, 0, stream>>>(partial, baseArr, nScan);
    k_scan_final<<<nScan, 256, 0, stream>>>(counts, baseArr, rowptr, cursor, N);
    k_fill<<<(E + 255) / 256, 256, 0, stream>>>(ei, t, lu, cursor, perm, srcp, relo, E);

    // node linears: q/k/v/skip in ONE staged-x launch
    const int nTN = (N + 31) / 32;
    k_node_mfma<<<min(nTN, 1024), 512, 0, stream>>>(
        (const float4*)x, Wq, Wk, Wv, Wsk, bq, bk, bv, bsk,
        qb, kb, vb, out, N, nTN);

    // edge GEMM: R7 gather structure, 256-edge tiles, 32 edges/wave
    const int nTE = (E + 255) / 256;
    k_edge_mfma<<<min(nTE, 1024), 512, 0, stream>>>(
        (const float4*)msg, relo,
        (const float4*)tw, (const float4*)tb, We, eb, E, nTE);

    // fused aggregation (e gathered via perm; no atomics)
    k_agg<<<(N + 3) / 4, 256, 0, stream>>>(
        srcp, perm, rowptr, counts,
        (const uint4*)qb, (const uint4*)kb, (const uint4*)vb, (const uint4*)eb,
        (float4*)out, N);
}

// Round 11
// 367.887 us; speedup vs baseline: 1.5900x; 1.1637x over previous
//
#include <hip/hip_runtime.h>
#include <math.h>

// ---------------------------------------------------------------------------
// GraphAttentionEmbedding (TGN TransformerConv, H=2, C=64, D=128, EDGE_DIM=256)
//   CSR build: hist -> scan -> fill (perm: slot->edge, srcp: slot->src,
//              relo: rel_t in ORIGINAL edge order)
//   K1 k_node_mfma (ONE launch): staged x-tile [32][128] bf16 in LDS;
//      [Wq|Wk|Wv|Wskip] in registers (wave w owns 64 of 512 cols)  [R9 proven]
//   K2 k_edge_mfma v3: canonical staged GEMM. LDS = We(64K) + msg-tile(16K)
//      = 80 KB -> 2 blocks/CU. Cooperative transient staging (4 float4/thread,
//      cvt, 2 ds_write) then pure {ds_read + MFMA} compute. No spill possible.
//   K3 k_agg: wave per dst; 4 edges/iter; no atomics on output  [R9 proven]
// ---------------------------------------------------------------------------

#define SCALE_ATTN 0.125f
#define SCAN_CHUNK 512

typedef __attribute__((ext_vector_type(8))) short bf16x8;
typedef __attribute__((ext_vector_type(4))) float f32x4;

union AFrag { bf16x8 v; unsigned short u[8]; };

__device__ __forceinline__ unsigned short f2bf(float f) {
    unsigned int u = __float_as_uint(f);
    u += 0x7fffu + ((u >> 16) & 1u);          // RNE
    return (unsigned short)(u >> 16);
}
__device__ __forceinline__ float bf2f(unsigned int lo16) {
    return __uint_as_float(lo16 << 16);
}
__device__ __forceinline__ void unpack8(uint4 u, float* f) {
    f[0] = bf2f(u.x & 0xffffu); f[1] = bf2f(u.x >> 16);
    f[2] = bf2f(u.y & 0xffffu); f[3] = bf2f(u.y >> 16);
    f[4] = bf2f(u.z & 0xffffu); f[5] = bf2f(u.z >> 16);
    f[6] = bf2f(u.w & 0xffffu); f[7] = bf2f(u.w >> 16);
}
__device__ __forceinline__ bf16x8 pack2(float4 a, float4 b) {
    AFrag f;
    f.u[0] = f2bf(a.x); f.u[1] = f2bf(a.y); f.u[2] = f2bf(a.z); f.u[3] = f2bf(a.w);
    f.u[4] = f2bf(b.x); f.u[5] = f2bf(b.y); f.u[6] = f2bf(b.z); f.u[7] = f2bf(b.w);
    return f.v;
}

// ---------------------------------------------------------------------------
// K1: all four node linears in ONE kernel. Block=512 (8 waves), tile=32 nodes.
// LDS: x-tile bf16 [32][128] swizzled (8 KB). Wave w owns 64 cols of the 512
// concatenated outputs (mat = w>>1: q,k,v,skip; half = w&1).
// ---------------------------------------------------------------------------
__global__ __launch_bounds__(512, 4) void k_node_mfma(
    const float4* __restrict__ x4,
    const float* __restrict__ Wq, const float* __restrict__ Wk,
    const float* __restrict__ Wv, const float* __restrict__ Ws,
    const float* __restrict__ bq, const float* __restrict__ bk,
    const float* __restrict__ bv, const float* __restrict__ bs,
    unsigned short* __restrict__ qb, unsigned short* __restrict__ kb,
    unsigned short* __restrict__ vb, float* __restrict__ outp,
    int N, int numTiles)
{
    __shared__ __align__(16) unsigned short sX[32 * 128];   // 8 KB
    const int tid = threadIdx.x;
    const int w = tid >> 6, l = tid & 63;
    const int l15 = l & 15, lg = l >> 4;
    const int mat = w >> 1;                 // 0 q, 1 k, 2 v, 3 skip
    const int colbase = (w & 1) * 64;       // within the 128-col matrix

    const float* Wm = (mat == 0) ? Wq : (mat == 1) ? Wk : (mat == 2) ? Wv : Ws;
    const float* bm = (mat == 0) ? bq : (mat == 1) ? bk : (mat == 2) ? bv : bs;

    // B fragments in registers
    bf16x8 Bf[4][4];
    float bias[4];
    #pragma unroll
    for (int nt = 0; nt < 4; ++nt) {
        const int col = colbase + nt * 16 + l15;
        bias[nt] = bm[col];
        #pragma unroll
        for (int ks = 0; ks < 4; ++ks) {
            AFrag f;
            #pragma unroll
            for (int j = 0; j < 8; ++j)
                f.u[j] = f2bf(Wm[(ks * 32 + lg * 8 + j) * 128 + col]);
            Bf[ks][nt] = f.v;
        }
    }

    for (int tile = blockIdx.x; tile < numTiles; tile += gridDim.x) {
        {
            const int e = tid >> 4, k8 = tid & 15;
            const int row = min(tile * 32 + e, N - 1);
            const float4 a0 = x4[(size_t)row * 32 + k8 * 2];
            const float4 a1 = x4[(size_t)row * 32 + k8 * 2 + 1];
            const int byteoff = (e * 256 + k8 * 16) ^ ((e & 7) << 4);
            *(bf16x8*)((char*)sX + byteoff) = pack2(a0, a1);
        }
        __syncthreads();

        f32x4 acc[2][4];
        #pragma unroll
        for (int m = 0; m < 2; ++m)
            #pragma unroll
            for (int nt = 0; nt < 4; ++nt) acc[m][nt] = (f32x4)(0.f);

        #pragma unroll
        for (int m = 0; m < 2; ++m) {
            const int lrow = m * 16 + l15;
            #pragma unroll
            for (int ks = 0; ks < 4; ++ks) {
                const int byteoff = (lrow * 256 + ks * 64 + lg * 16) ^ ((lrow & 7) << 4);
                const bf16x8 a = *(const bf16x8*)((const char*)sX + byteoff);
                #pragma unroll
                for (int nt = 0; nt < 4; ++nt)
                    acc[m][nt] = __builtin_amdgcn_mfma_f32_16x16x32_bf16(a, Bf[ks][nt], acc[m][nt], 0, 0, 0);
            }
        }

        #pragma unroll
        for (int m = 0; m < 2; ++m) {
            #pragma unroll
            for (int nt = 0; nt < 4; ++nt) {
                const int col = colbase + nt * 16 + l15;
                #pragma unroll
                for (int r = 0; r < 4; ++r) {
                    const int node = tile * 32 + m * 16 + lg * 4 + r;
                    if (node < N) {
                        const float val = acc[m][nt][r] + bias[nt];
                        if (mat == 0)      qb[(size_t)node * 128 + col] = f2bf(val);
                        else if (mat == 1) kb[(size_t)node * 128 + col] = f2bf(val);
                        else if (mat == 2) vb[(size_t)node * 128 + col] = f2bf(val);
                        else               outp[(size_t)node * 128 + col] = val;
                    }
                }
            }
        }
        __syncthreads();
    }
}

// ---------------------------------------------------------------------------
// K2 v3: canonical staged edge GEMM. Block=512 (8 waves), tile = 64 edges.
// LDS: sWe bf16 [128 n][256 k] swizzled (64 KB) + sMsg bf16 [64 e][128 k]
// swizzled (16 KB) = 80 KB -> 2 blocks/CU (16 waves/CU).
// Stage: each thread 4 coalesced float4 -> cvt -> 2 ds_write (transient).
// Compute: wave = (msub = w>>1 edge rows, colhalf = w&1); per kk: 8 cos +
// 4 MFMA (cos half) + 1 swizzled ds_read + 4 MFMA (msg half). acc = 16 VGPR.
// All reads/writes sequential in edge order; coverage by construction.
// ---------------------------------------------------------------------------
__global__ __launch_bounds__(512, 4) void k_edge_mfma(
    const float4* __restrict__ msg4,
    const float* __restrict__ relo,
    const float4* __restrict__ tw4, const float4* __restrict__ tb4,
    const float* __restrict__ We,
    unsigned short* __restrict__ ebuf, int E, int numTiles)
{
    __shared__ __align__(16) unsigned short sWe[128 * 256];   // 64 KB
    __shared__ __align__(16) unsigned short sMsg[64 * 128];   // 16 KB
    const int tid = threadIdx.x;
    const int w = tid >> 6, l = tid & 63;
    const int l15 = l & 15, lg = l >> 4;
    const int msub = w >> 1;              // edge subtile (16 rows)
    const int colbase = (w & 1) * 64;     // output col half

    // stage We^T bf16 swizzled: [n=128][k=256], row stride 512 B
    for (int c = tid; c < 4096; c += 512) {
        const int n = c >> 5, k0 = (c & 31) << 3;
        AFrag af;
        #pragma unroll
        for (int j = 0; j < 8; ++j) af.u[j] = f2bf(We[(k0 + j) * 128 + n]);
        const int byteoff = ((n << 9) + (k0 << 1)) ^ ((n & 7) << 4);
        *(bf16x8*)((char*)sWe + byteoff) = af.v;
    }
    __syncthreads();

    const int nrow = colbase + l15;                      // We row for B-frags
    const int swzW = (nrow & 7) << 4;

    for (int tile = blockIdx.x; tile < numTiles; tile += gridDim.x) {
        const int ebase = tile * 64;

        // ---- stage msg tile: unit U = 16 bf16 (row e, 16B-unit u), swizzled
        #pragma unroll
        for (int i = 0; i < 2; ++i) {
            const int U = tid * 2 + i;                   // 0..1023
            const int e = U >> 4, u = U & 15;
            const int er = min(ebase + e, E - 1);
            const float4 a0 = msg4[(size_t)er * 32 + u * 2];
            const float4 a1 = msg4[(size_t)er * 32 + u * 2 + 1];
            const int byteoff = (e << 8) + ((u ^ (e & 7)) << 4);
            *(bf16x8*)((char*)sMsg + byteoff) = pack2(a0, a1);
        }
        __syncthreads();

        // ---- compute
        const int erow = ebase + msub * 16 + l15;
        const float rel = relo[min(erow, E - 1)];

        f32x4 acc[4];
        #pragma unroll
        for (int i = 0; i < 4; ++i) acc[i] = (f32x4)(0.f);

        #pragma unroll
        for (int kk = 0; kk < 4; ++kk) {
            const int kbase = (kk << 5) + (lg << 3);     // bf16 k index

            // cos A-frag (VALU only)
            const float4 tww = tw4[kbase >> 2];
            const float4 tw2 = tw4[(kbase >> 2) + 1];
            const float4 tbb = tb4[kbase >> 2];
            const float4 tb2 = tb4[(kbase >> 2) + 1];
            AFrag a;
            a.u[0] = f2bf(__cosf(fmaf(rel, tww.x, tbb.x)));
            a.u[1] = f2bf(__cosf(fmaf(rel, tww.y, tbb.y)));
            a.u[2] = f2bf(__cosf(fmaf(rel, tww.z, tbb.z)));
            a.u[3] = f2bf(__cosf(fmaf(rel, tww.w, tbb.w)));
            a.u[4] = f2bf(__cosf(fmaf(rel, tw2.x, tb2.x)));
            a.u[5] = f2bf(__cosf(fmaf(rel, tw2.y, tb2.y)));
            a.u[6] = f2bf(__cosf(fmaf(rel, tw2.z, tb2.z)));
            a.u[7] = f2bf(__cosf(fmaf(rel, tw2.w, tb2.w)));
            const int bC = ((nrow << 9) + (kbase << 1)) ^ swzW;
            #pragma unroll
            for (int nt = 0; nt < 4; ++nt) {
                const bf16x8 b = *(const bf16x8*)((const char*)sWe + (bC + (nt << 13)));
                acc[nt] = __builtin_amdgcn_mfma_f32_16x16x32_bf16(a.v, b, acc[nt], 0, 0, 0);
            }

            // msg A-frag from staged LDS (swizzled read)
            const int me = msub * 16 + l15;
            const int mu = (kk << 2) + lg;
            const int mbyte = (me << 8) + ((mu ^ (me & 7)) << 4);
            const bf16x8 am = *(const bf16x8*)((const char*)sMsg + mbyte);
            const int bM = ((nrow << 9) + ((128 + kbase) << 1)) ^ swzW;
            #pragma unroll
            for (int nt = 0; nt < 4; ++nt) {
                const bf16x8 b = *(const bf16x8*)((const char*)sWe + (bM + (nt << 13)));
                acc[nt] = __builtin_amdgcn_mfma_f32_16x16x32_bf16(am, b, acc[nt], 0, 0, 0);
            }
        }

        // ---- epilogue: sequential edge rows (coverage by construction)
        #pragma unroll
        for (int nt = 0; nt < 4; ++nt) {
            const int col = colbase + nt * 16 + l15;
            #pragma unroll
            for (int r = 0; r < 4; ++r) {
                const int er = ebase + msub * 16 + (lg << 2) + r;
                if (er < E) ebuf[(size_t)er * 128 + col] = f2bf(acc[nt][r]);
            }
        }
        __syncthreads();   // before next tile's stage overwrites sMsg
    }
}

// ---------------------------------------------------------------------------
// CSR build
// ---------------------------------------------------------------------------
__global__ __launch_bounds__(256) void k_hist(
    const int* __restrict__ ei, int* __restrict__ counts, int E)
{
    int i = blockIdx.x * 256 + threadIdx.x;
    if (i < E) atomicAdd(&counts[ei[E + i]], 1);
}

__global__ __launch_bounds__(256) void k_scan_partial(
    const int* __restrict__ counts, int* __restrict__ partial, int N)
{
    const int base = blockIdx.x * SCAN_CHUNK;
    int v = 0;
    for (int i = threadIdx.x; i < SCAN_CHUNK; i += 256) {
        const int idx = base + i;
        if (idx < N) v += counts[idx];
    }
    __shared__ int red[4];
    #pragma unroll
    for (int off = 1; off < 64; off <<= 1) v += __shfl_xor(v, off);
    if ((threadIdx.x & 63) == 0) red[threadIdx.x >> 6] = v;
    __syncthreads();
    if (threadIdx.x == 0) partial[blockIdx.x] = red[0] + red[1] + red[2] + red[3];
}

__global__ __launch_bounds__(256) void k_scan_base(
    const int* __restrict__ partial, int* __restrict__ base, int nb)
{
    __shared__ int tmp[256];
    const int v = (threadIdx.x < nb) ? partial[threadIdx.x] : 0;
    tmp[threadIdx.x] = v;
    __syncthreads();
    for (int off = 1; off < 256; off <<= 1) {
        const int add = (threadIdx.x >= off) ? tmp[threadIdx.x - off] : 0;
        __syncthreads();
        tmp[threadIdx.x] += add;
        __syncthreads();
    }
    if (threadIdx.x < nb) base[threadIdx.x] = tmp[threadIdx.x] - v;
}

__global__ __launch_bounds__(256) void k_scan_final(
    const int* __restrict__ counts, const int* __restrict__ base,
    int* __restrict__ rowptr, int* __restrict__ cursor, int N)
{
    const int i0 = blockIdx.x * SCAN_CHUNK;
    __shared__ int tmp[256];
    const int ia = i0 + threadIdx.x * 2, ib = ia + 1;
    const int v0 = (ia < N) ? counts[ia] : 0;
    const int v1 = (ib < N) ? counts[ib] : 0;
    const int s = v0 + v1;
    tmp[threadIdx.x] = s;
    __syncthreads();
    for (int off = 1; off < 256; off <<= 1) {
        const int add = (threadIdx.x >= off) ? tmp[threadIdx.x - off] : 0;
        __syncthreads();
        tmp[threadIdx.x] += add;
        __syncthreads();
    }
    const int excl = tmp[threadIdx.x] - s + base[blockIdx.x];
    if (ia < N) { rowptr[ia] = excl;      cursor[ia] = excl; }
    if (ib < N) { rowptr[ib] = excl + v0; cursor[ib] = excl + v0; }
}

// fill: perm (slot -> edge), srcp (slot -> src), relo (original edge order)
__global__ __launch_bounds__(256) void k_fill(
    const int* __restrict__ ei, const float* __restrict__ t,
    const float* __restrict__ lu, int* __restrict__ cursor,
    int* __restrict__ perm, int* __restrict__ srcp,
    float* __restrict__ relo, int E)
{
    int i = blockIdx.x * 256 + threadIdx.x;
    if (i < E) {
        const int s = ei[i];
        const int d = ei[E + i];
        const int pos = atomicAdd(&cursor[d], 1);
        perm[pos] = i;
        srcp[pos] = s;
        relo[i] = t[i] - lu[s];
    }
}

// ---------------------------------------------------------------------------
// K3: fused aggregation. One wave per dst. Lane = (eg = l>>4 edge group,
// s16 = l&15 16B slot in the 256B row). 4 edges per iteration, 3 independent
// uint4 loads each. Logit reduce xor{1,2,4} within the 8-lane head slice;
// final cross-group combine xor{16,32}.
// ---------------------------------------------------------------------------
__global__ __launch_bounds__(256) void k_agg(
    const int* __restrict__ srcp, const int* __restrict__ perm,
    const int* __restrict__ rowptr, const int* __restrict__ counts,
    const uint4* __restrict__ qb4, const uint4* __restrict__ kb4,
    const uint4* __restrict__ vb4, const uint4* __restrict__ eb4,
    float4* __restrict__ out4, int N)
{
    const int d = blockIdx.x * 4 + (threadIdx.x >> 6);
    if (d >= N) return;
    const int l = threadIdx.x & 63;
    const int s16 = l & 15;       // 16B slot (8 channels)
    const int eg = l >> 4;        // edge group 0..3
    const int start = rowptr[d];
    const int deg = counts[d];

    float qf[8];
    unpack8(qb4[(size_t)d * 16 + s16], qf);
    float accf[8] = {0.f, 0.f, 0.f, 0.f, 0.f, 0.f, 0.f, 0.f};
    float denom = 0.f;

    for (int cbase = 0; cbase < deg; cbase += 64) {
        const int clen = min(deg - cbase, 64);
        int mySrc = 0, myEid = 0;
        if (l < clen) {
            mySrc = srcp[start + cbase + l];   // coalesced
            myEid = perm[start + cbase + l];   // coalesced
        }

        #pragma unroll 2
        for (int i = 0; i < clen; i += 4) {
            const int off = i + eg;
            const bool valid = off < clen;
            const int offc = valid ? off : 0;
            const int src = __shfl(mySrc, offc);
            const int eid = __shfl(myEid, offc);
            float kf[8], ef[8], vf[8];
            unpack8(kb4[(size_t)src * 16 + s16], kf);
            unpack8(eb4[(size_t)eid * 16 + s16], ef);
            unpack8(vb4[(size_t)src * 16 + s16], vf);
            float s = 0.f;
            #pragma unroll
            for (int j = 0; j < 8; ++j) s = fmaf(qf[j], kf[j] + ef[j], s);
            s += __shfl_xor(s, 1);
            s += __shfl_xor(s, 2);
            s += __shfl_xor(s, 4);
            const float p = valid ? __expf(s * SCALE_ATTN) : 0.f;
            denom += p;
            #pragma unroll
            for (int j = 0; j < 8; ++j) accf[j] = fmaf(p, vf[j] + ef[j], accf[j]);
        }
    }
    #pragma unroll
    for (int j = 0; j < 8; ++j) {
        accf[j] += __shfl_xor(accf[j], 16);
        accf[j] += __shfl_xor(accf[j], 32);
    }
    denom += __shfl_xor(denom, 16);
    denom += __shfl_xor(denom, 32);

    if (l < 16) {
        const float inv = 1.f / (denom + 1e-16f);
        float4* o = out4 + (size_t)d * 32 + s16 * 2;
        const float4 c0 = o[0];
        const float4 c1 = o[1];
        o[0] = make_float4(fmaf(accf[0], inv, c0.x), fmaf(accf[1], inv, c0.y),
                           fmaf(accf[2], inv, c0.z), fmaf(accf[3], inv, c0.w));
        o[1] = make_float4(fmaf(accf[4], inv, c1.x), fmaf(accf[5], inv, c1.y),
                           fmaf(accf[6], inv, c1.z), fmaf(accf[7], inv, c1.w));
    }
}

// ---------------------------------------------------------------------------
extern "C" void kernel_launch(void* const* d_in, const int* in_sizes, int n_in,
                              void* d_out, int out_size, void* d_ws, size_t ws_size,
                              hipStream_t stream)
{
    const float* x   = (const float*)d_in[0];
    const float* lu  = (const float*)d_in[1];
    const int*   ei  = (const int*)d_in[2];
    const float* t   = (const float*)d_in[3];
    const float* msg = (const float*)d_in[4];
    const float* tw  = (const float*)d_in[5];
    const float* tb  = (const float*)d_in[6];
    const float* Wq  = (const float*)d_in[7];
    const float* bq  = (const float*)d_in[8];
    const float* Wk  = (const float*)d_in[9];
    const float* bk  = (const float*)d_in[10];
    const float* Wv  = (const float*)d_in[11];
    const float* bv  = (const float*)d_in[12];
    const float* We  = (const float*)d_in[13];
    const float* Wsk = (const float*)d_in[14];
    const float* bsk = (const float*)d_in[15];

    const int N = in_sizes[1];   // last_update: N elements
    const int E = in_sizes[3];   // t: E elements
    float* out = (float*)d_out;

    char* ws = (char*)d_ws;
    unsigned short* qb = (unsigned short*)ws;  ws += (size_t)N * 128 * sizeof(unsigned short);
    unsigned short* kb = (unsigned short*)ws;  ws += (size_t)N * 128 * sizeof(unsigned short);
    unsigned short* vb = (unsigned short*)ws;  ws += (size_t)N * 128 * sizeof(unsigned short);
    unsigned short* eb = (unsigned short*)ws;  ws += (size_t)E * 128 * sizeof(unsigned short);
    int*   counts  = (int*)ws;   ws += (size_t)N * sizeof(int);
    int*   rowptr  = (int*)ws;   ws += (size_t)N * sizeof(int);
    int*   cursor  = (int*)ws;   ws += (size_t)N * sizeof(int);
    int*   perm    = (int*)ws;   ws += (size_t)E * sizeof(int);
    int*   srcp    = (int*)ws;   ws += (size_t)E * sizeof(int);
    float* relo    = (float*)ws; ws += (size_t)E * sizeof(float);
    int*   partial = (int*)ws;   ws += 512 * sizeof(int);
    int*   baseArr = (int*)ws;   ws += 512 * sizeof(int);

    const int nScan = (N + SCAN_CHUNK - 1) / SCAN_CHUNK;

    hipMemsetAsync(counts, 0, (size_t)N * sizeof(int), stream);

    // CSR build (k_edge needs relo; k_agg needs perm/srcp/rowptr/counts)
    k_hist<<<(E + 255) / 256, 256, 0, stream>>>(ei, counts, E);
    k_scan_partial<<<nScan, 256, 0, stream>>>(counts, partial, N);
    k_scan_base<<<1, 256, 0, stream>>>(partial, baseArr, nScan);
    k_scan_final<<<nScan, 256, 0, stream>>>(counts, baseArr, rowptr, cursor, N);
    k_fill<<<(E + 255) / 256, 256, 0, stream>>>(ei, t, lu, cursor, perm, srcp, relo, E);

    // node linears: q/k/v/skip in ONE staged-x launch
    const int nTN = (N + 31) / 32;
    k_node_mfma<<<min(nTN, 1024), 512, 0, stream>>>(
        (const float4*)x, Wq, Wk, Wv, Wsk, bq, bk, bv, bsk,
        qb, kb, vb, out, N, nTN);

    // edge GEMM v3: staged tiles of 64 edges, 2 blocks/CU
    const int nTE = (E + 63) / 64;
    k_edge_mfma<<<min(nTE, 512), 512, 0, stream>>>(
        (const float4*)msg, relo,
        (const float4*)tw, (const float4*)tb, We, eb, E, nTE);

    // fused aggregation (e gathered via perm; no atomics)
    k_agg<<<(N + 3) / 4, 256, 0, stream>>>(
        srcp, perm, rowptr, counts,
        (const uint4*)qb, (const uint4*)kb, (const uint4*)vb, (const uint4*)eb,
        (float4*)out, N);
}